// Round 1
// baseline (175.969 us; speedup 1.0000x reference)
//
#include <hip/hip_runtime.h>

// Problem constants (B=4, N=512, D_in=512, D_out=256), fp32 in/out.
constexpr int Bq   = 4;
constexpr int Nq   = 512;
constexpr int DIN  = 512;
constexpr int DOUT = 256;
constexpr int TI   = 8;     // query rows per block

// ---------------------------------------------------------------------------
// K1: Wh[b,n,o] = dot(H[b,n,:], W[o,:]);  also WhT[b,o,n] = Wh[b,n,o]
// grid 256 blocks (8 rows each), 256 threads (thread = o).
// H rows are block-uniform -> scalar loads; W read per-lane float4.
// ---------------------------------------------------------------------------
__global__ __launch_bounds__(256) void k1_wh(const float* __restrict__ H,
                                             const float* __restrict__ W,
                                             float* __restrict__ Wh,
                                             float* __restrict__ WhT) {
    const int t   = threadIdx.x;          // o index
    const int blk = blockIdx.x;           // 0..255
    const int b   = blk >> 6;
    const int n0  = (blk & 63) << 3;      // 8 rows per block

    const float4* __restrict__ W4 = (const float4*)(W + t * DIN);

    const float4* hrow[TI];
#pragma unroll
    for (int r = 0; r < TI; ++r)
        hrow[r] = (const float4*)(H + ((size_t)(b * Nq) + n0 + r) * DIN);

    float acc[TI];
#pragma unroll
    for (int r = 0; r < TI; ++r) acc[r] = 0.f;

    for (int kc = 0; kc < DIN / 4; ++kc) {
        float4 wv = W4[kc];
#pragma unroll
        for (int r = 0; r < TI; ++r) {
            float4 hv = hrow[r][kc];      // uniform -> s_load_dwordx4
            acc[r] += hv.x * wv.x + hv.y * wv.y + hv.z * wv.z + hv.w * wv.w;
        }
    }

#pragma unroll
    for (int r = 0; r < TI; ++r)
        Wh[((b * Nq) + n0 + r) * DOUT + t] = acc[r];   // coalesced

    // WhT[b][o][n]; n0 is a multiple of 8 -> 16B-aligned float4 stores
    float4* wt4 = (float4*)(WhT + ((size_t)(b * DOUT) + t) * Nq + n0);
    wt4[0] = make_float4(acc[0], acc[1], acc[2], acc[3]);
    wt4[1] = make_float4(acc[4], acc[5], acc[6], acc[7]);
}

// ---------------------------------------------------------------------------
// K2: e + softmax -> P (normalized attention).
// e[i,j] = 0.6*(r_i + r_j) + 0.4 * sum_o a[o]*|Wh_i[o]+Wh_j[o]|,  r_n = a.Wh_n
// Block = (b, i0..i0+7); thread t owns j in {t, t+256}.
// Wh_i rows + a are block-uniform -> scalar loads; WhT reads coalesced.
// ---------------------------------------------------------------------------
__global__ __launch_bounds__(256) void k2_attn(const float* __restrict__ Wh,
                                               const float* __restrict__ WhT,
                                               const float* __restrict__ a,
                                               float* __restrict__ P) {
    const int t   = threadIdx.x;
    const int blk = blockIdx.x;
    const int b   = blk >> 6;
    const int i0  = (blk & 63) << 3;
    const int j0  = t;
    const int j1  = t + 256;

    const float4* __restrict__ a4 = (const float4*)a;
    const float4* wi4[TI];
#pragma unroll
    for (int r = 0; r < TI; ++r)
        wi4[r] = (const float4*)(Wh + ((size_t)(b * Nq) + i0 + r) * DOUT);

    const float* __restrict__ wt = WhT + (size_t)(b * DOUT) * Nq;

    float absacc0[TI], absacc1[TI];
#pragma unroll
    for (int r = 0; r < TI; ++r) { absacc0[r] = 0.f; absacc1[r] = 0.f; }
    float racc0 = 0.f, racc1 = 0.f;

    for (int oc = 0; oc < DOUT / 4; ++oc) {
        float4 av = a4[oc];               // uniform
        float4 wiv[TI];
#pragma unroll
        for (int r = 0; r < TI; ++r) wiv[r] = wi4[r][oc];  // uniform
#pragma unroll
        for (int q = 0; q < 4; ++q) {
            const int o   = oc * 4 + q;
            const float aq = ((const float*)&av)[q];
            const float wj0 = wt[o * Nq + j0];    // coalesced
            const float wj1 = wt[o * Nq + j1];    // coalesced
            racc0 += aq * wj0;
            racc1 += aq * wj1;
#pragma unroll
            for (int r = 0; r < TI; ++r) {
                const float wir = ((const float*)&wiv[r])[q];
                absacc0[r] += aq * fabsf(wir + wj0);  // v_fma with |src|
                absacc1[r] += aq * fabsf(wir + wj1);
            }
        }
    }

    // share r_j so each block can read r_i for its 8 query rows
    __shared__ float rbuf[Nq];
    rbuf[j0] = racc0;
    rbuf[j1] = racc1;
    __syncthreads();

    float e0[TI], e1[TI];
#pragma unroll
    for (int r = 0; r < TI; ++r) {
        const float ri = rbuf[i0 + r];
        e0[r] = 0.6f * (ri + racc0) + 0.4f * absacc0[r];
        e1[r] = 0.6f * (ri + racc1) + 0.4f * absacc1[r];
    }

    // row max: wave64 shuffle reduce, then cross-wave via LDS
    __shared__ float wred[TI][4];
    const int wid  = t >> 6;
    const int lane = t & 63;

    float lm[TI];
#pragma unroll
    for (int r = 0; r < TI; ++r) lm[r] = fmaxf(e0[r], e1[r]);
#pragma unroll
    for (int off = 32; off > 0; off >>= 1) {
#pragma unroll
        for (int r = 0; r < TI; ++r)
            lm[r] = fmaxf(lm[r], __shfl_xor(lm[r], off, 64));
    }
    if (lane == 0) {
#pragma unroll
        for (int r = 0; r < TI; ++r) wred[r][wid] = lm[r];
    }
    __syncthreads();
    float m[TI];
#pragma unroll
    for (int r = 0; r < TI; ++r)
        m[r] = fmaxf(fmaxf(wred[r][0], wred[r][1]), fmaxf(wred[r][2], wred[r][3]));
    __syncthreads();   // wred reused below

    float p0[TI], p1[TI], ls[TI];
#pragma unroll
    for (int r = 0; r < TI; ++r) {
        p0[r] = __expf(e0[r] - m[r]);
        p1[r] = __expf(e1[r] - m[r]);
        ls[r] = p0[r] + p1[r];
    }
#pragma unroll
    for (int off = 32; off > 0; off >>= 1) {
#pragma unroll
        for (int r = 0; r < TI; ++r)
            ls[r] += __shfl_xor(ls[r], off, 64);
    }
    if (lane == 0) {
#pragma unroll
        for (int r = 0; r < TI; ++r) wred[r][wid] = ls[r];
    }
    __syncthreads();
#pragma unroll
    for (int r = 0; r < TI; ++r) {
        const float s   = wred[r][0] + wred[r][1] + wred[r][2] + wred[r][3];
        const float inv = 1.0f / s;
        float* prow = P + ((size_t)(b * Nq) + i0 + r) * Nq;
        prow[j0] = p0[r] * inv;           // coalesced
        prow[j1] = p1[r] * inv;
    }
}

// ---------------------------------------------------------------------------
// K3: out[b,i,o] = sum_j P[b,i,j] * Wh[b,j,o]
// Block = (b, i0..i0+7); thread = o. P rows block-uniform -> scalar loads.
// ---------------------------------------------------------------------------
__global__ __launch_bounds__(256) void k3_av(const float* __restrict__ Wh,
                                             const float* __restrict__ P,
                                             float* __restrict__ out) {
    const int t   = threadIdx.x;          // o
    const int blk = blockIdx.x;
    const int b   = blk >> 6;
    const int i0  = (blk & 63) << 3;

    const float4* p4[TI];
#pragma unroll
    for (int r = 0; r < TI; ++r)
        p4[r] = (const float4*)(P + ((size_t)(b * Nq) + i0 + r) * Nq);

    const float* __restrict__ whb = Wh + (size_t)(b * Nq) * DOUT + t;

    float acc[TI];
#pragma unroll
    for (int r = 0; r < TI; ++r) acc[r] = 0.f;

    for (int jc = 0; jc < Nq / 4; ++jc) {
        float4 pv[TI];
#pragma unroll
        for (int r = 0; r < TI; ++r) pv[r] = p4[r][jc];   // uniform
#pragma unroll
        for (int q = 0; q < 4; ++q) {
            const int j = jc * 4 + q;
            const float whv = whb[j * DOUT];              // coalesced
#pragma unroll
            for (int r = 0; r < TI; ++r)
                acc[r] += ((const float*)&pv[r])[q] * whv;
        }
    }

#pragma unroll
    for (int r = 0; r < TI; ++r)
        out[((b * Nq) + i0 + r) * DOUT + t] = acc[r];     // coalesced
}

// ---------------------------------------------------------------------------
extern "C" void kernel_launch(void* const* d_in, const int* in_sizes, int n_in,
                              void* d_out, int out_size, void* d_ws, size_t ws_size,
                              hipStream_t stream) {
    const float* H = (const float*)d_in[0];   // [4,512,512]
    const float* W = (const float*)d_in[1];   // [256,512]
    const float* a = (const float*)d_in[2];   // [256,1]
    float* out = (float*)d_out;               // [4,512,256]

    float* Wh  = (float*)d_ws;                 // 524288 floats (2 MB)
    float* WhT = Wh  + Bq * Nq * DOUT;         // 524288 floats (2 MB)
    float* P   = WhT + Bq * Nq * DOUT;         // 1048576 floats (4 MB)

    const dim3 grid(Bq * Nq / TI);             // 256 blocks
    const dim3 block(256);

    hipLaunchKernelGGL(k1_wh,   grid, block, 0, stream, H, W, Wh, WhT);
    hipLaunchKernelGGL(k2_attn, grid, block, 0, stream, Wh, WhT, a, P);
    hipLaunchKernelGGL(k3_av,   grid, block, 0, stream, Wh, P, out);
}